// Round 5
// baseline (145.262 us; speedup 1.0000x reference)
//
#include <hip/hip_runtime.h>
#include <hip/hip_bf16.h>
#include <math.h>

typedef __bf16 bf16x8 __attribute__((ext_vector_type(8)));
typedef __bf16 bf16x4 __attribute__((ext_vector_type(4)));
typedef float  f32x4  __attribute__((ext_vector_type(4)));

constexpr int Nn = 8192;   // B*S
constexpr int Dd = 256;    // feature dim
constexpr float LOG2E     = 1.4426950408889634f;
constexpr float SIM_SCALE = 20.0f * LOG2E;   // (1/tau)*log2(e), tau=0.05
constexpr float SIM_BIAS  = -20.0f * LOG2E;  // fixed max = 1/tau (|q.k|<=1)

// async global->LDS DMA, 16B per lane. LDS dst = wave-uniform base + lane*16
// (HW constraint). Casts are the production CK idiom (inttoptr; flat-LDS
// low 32 bits == LDS offset on gfx9+).
typedef __attribute__((address_space(1))) const unsigned int gu32;
typedef __attribute__((address_space(3))) unsigned int lu32;
__device__ __forceinline__ void gload16(const __bf16* g, __bf16* l) {
  __builtin_amdgcn_global_load_lds((gu32*)(uintptr_t)g, (lu32*)(uintptr_t)l, 16, 0, 0);
}

// ---------------------------------------------------------------------------
// Kernel 1: L2-normalize rows -> bf16; also init cbias / accumulators.
// ---------------------------------------------------------------------------
__global__ __launch_bounds__(256) void prep_kernel(const float* __restrict__ logits,
                                                   const float* __restrict__ labels,
                                                   const int* __restrict__ pad,
                                                   __bf16* __restrict__ qb,
                                                   __bf16* __restrict__ kb,
                                                   float* __restrict__ cbias,
                                                   float* __restrict__ g_all,
                                                   float* __restrict__ g_pos) {
  const int j = blockIdx.x * 256 + threadIdx.x;
  if (j < Nn) {
    cbias[j] = pad[j] ? 0.0f : -1e30f;
    g_all[j] = 0.0f;
    g_pos[j] = 0.0f;
  }

  const int gw   = (blockIdx.x * 256 + threadIdx.x) >> 6;
  const int lane = threadIdx.x & 63;
  const float* src;
  __bf16* dst;
  int row;
  if (gw < Nn) { src = logits; dst = qb; row = gw; }
  else         { src = labels; dst = kb; row = gw - Nn; }

  const float4 v = *reinterpret_cast<const float4*>(src + (size_t)row * Dd + lane * 4);
  float ss = v.x * v.x + v.y * v.y + v.z * v.z + v.w * v.w;
#pragma unroll
  for (int m = 32; m >= 1; m >>= 1) ss += __shfl_xor(ss, m);
  const float scale = 1.0f / fmaxf(sqrtf(ss), 1e-12f);

  bf16x4 o;
  o[0] = (__bf16)(v.x * scale);
  o[1] = (__bf16)(v.y * scale);
  o[2] = (__bf16)(v.z * scale);
  o[3] = (__bf16)(v.w * scale);
  *reinterpret_cast<bf16x4*>(dst + (size_t)row * Dd + lane * 4) = o;
}

// ---------------------------------------------------------------------------
// Kernel 2: fused sim = Q K^T / tau + masked exp-sum epilogue.
// Grid (64,64): one 128x128 output tile per block. BK=64, 4 K-steps.
// Staging via global_load_lds(16B): wave w, iter i fills 8 contiguous LDS
// rows [w*32+i*8, +8); lane l loads global row +(l>>3), logical 16B-group
// (l&7)^(l>>3) -> lands at the XOR-swizzled slot (group' = c ^ (row&7))
// the read side expects. Read side identical to R4 (verified, 0 conflicts).
// ONLY change vs R4: staging path (VGPR round-trip -> LDS DMA).
// ---------------------------------------------------------------------------
__global__ __launch_bounds__(256) void gemm_lse_kernel(const __bf16* __restrict__ qb,
                                                       const __bf16* __restrict__ kb,
                                                       const float* __restrict__ cbias,
                                                       const int* __restrict__ ad,
                                                       float* __restrict__ g_all,
                                                       float* __restrict__ g_pos) {
  __shared__ __bf16 As[128 * 64];  // 16 KiB
  __shared__ __bf16 Bs[128 * 64];  // 16 KiB
  __shared__ float sA[128], sP[128];

  const int tid  = threadIdx.x;
  const int lane = tid & 63;
  const int w    = tid >> 6;
  const int wrow = (w >> 1) * 64;
  const int wcol = (w & 1) * 64;
  const int lq   = lane & 15;
  const int qd   = lane >> 4;
  const int rowBase = blockIdx.x * 128;
  const int colBase = blockIdx.y * 128;

  if (tid < 128) { sA[tid] = 0.0f; sP[tid] = 0.0f; }

  // per-lane staging constants
  const int srl = lane >> 3;                  // row within 8-row chunk
  const int cg  = (lane & 7) ^ srl;           // logical 16B group to fetch
  const __bf16* gA0 = qb + (size_t)(rowBase + w * 32 + srl) * Dd + cg * 8;
  const __bf16* gB0 = kb + (size_t)(colBase + w * 32 + srl) * Dd + cg * 8;

  f32x4 c[4][4];
#pragma unroll
  for (int mt = 0; mt < 4; ++mt)
#pragma unroll
    for (int nt = 0; nt < 4; ++nt)
      c[mt][nt] = (f32x4){0.f, 0.f, 0.f, 0.f};

  for (int kk = 0; kk < 4; ++kk) {
    const int kOff = kk * 64;
    __syncthreads();  // prior MFMA phase done reading LDS
#pragma unroll
    for (int i = 0; i < 4; ++i) {
      gload16(gA0 + (size_t)i * 8 * Dd + kOff, &As[(w * 32 + i * 8) * 64]);
      gload16(gB0 + (size_t)i * 8 * Dd + kOff, &Bs[(w * 32 + i * 8) * 64]);
    }
    __syncthreads();  // drains vmcnt (global_load_lds) before reads

#pragma unroll
    for (int kq = 0; kq < 2; ++kq) {
      bf16x8 af[4], bfq[4];
      const int lg = kq * 4 + qd;  // logical 16B group within BK=64
#pragma unroll
      for (int mt = 0; mt < 4; ++mt) {
        const int r = wrow + mt * 16 + lq;
        af[mt] = *reinterpret_cast<const bf16x8*>(&As[r * 64 + (lg ^ (r & 7)) * 8]);
      }
#pragma unroll
      for (int nt = 0; nt < 4; ++nt) {
        const int r = wcol + nt * 16 + lq;
        bfq[nt] = *reinterpret_cast<const bf16x8*>(&Bs[r * 64 + (lg ^ (r & 7)) * 8]);
      }
#pragma unroll
      for (int mt = 0; mt < 4; ++mt)
#pragma unroll
        for (int nt = 0; nt < 4; ++nt)
          c[mt][nt] = __builtin_amdgcn_mfma_f32_16x16x32_bf16(af[mt], bfq[nt], c[mt][nt], 0, 0, 0);
    }
  }

  // epilogue: e = exp(sim - 20), invalid cols -> 0 via cbias = -1e30;
  // reduce over nt and the 16 col-lanes, combine rows in LDS, 1 atomic/row.
  float colB[4];
  int colAd[4];
#pragma unroll
  for (int nt = 0; nt < 4; ++nt) {
    const int col = colBase + wcol + nt * 16 + lq;
    colB[nt]  = SIM_BIAS + cbias[col];
    colAd[nt] = ad[col];
  }

#pragma unroll
  for (int mt = 0; mt < 4; ++mt) {
#pragma unroll
    for (int r = 0; r < 4; ++r) {
      const int rowAd = ad[rowBase + wrow + mt * 16 + qd * 4 + r];
      float a = 0.f, p = 0.f;
#pragma unroll
      for (int nt = 0; nt < 4; ++nt) {
        const float e = exp2f(fmaf(c[mt][nt][r], SIM_SCALE, colB[nt]));
        a += e;
        p += (colAd[nt] == rowAd) ? e : 0.f;
      }
#pragma unroll
      for (int m = 1; m < 16; m <<= 1) {
        a += __shfl_xor(a, m);
        p += __shfl_xor(p, m);
      }
      if (lq == 0) {
        const int row = wrow + mt * 16 + qd * 4 + r;
        atomicAdd(&sA[row], a);
        atomicAdd(&sP[row], p);
      }
    }
  }
  __syncthreads();
  if (tid < 128) {
    atomicAdd(&g_all[rowBase + tid], sA[tid]);
    atomicAdd(&g_pos[rowBase + tid], sP[tid]);
  }
}

// ---------------------------------------------------------------------------
// Kernel 3: loss = mean over valid rows of log(g_all) - log(g_pos).
// ---------------------------------------------------------------------------
__global__ __launch_bounds__(1024) void reduce_kernel(const float* __restrict__ g_all,
                                                      const float* __restrict__ g_pos,
                                                      const int* __restrict__ pad,
                                                      float* __restrict__ out) {
  __shared__ float sS[16], sC[16];
  const int t = threadIdx.x;
  float s = 0.f, c = 0.f;
  const float4* ga4 = (const float4*)g_all;
  const float4* gp4 = (const float4*)g_pos;
  const int4*   pd4 = (const int4*)pad;
  for (int i = t; i < Nn / 4; i += 1024) {
    const float4 ga = ga4[i];
    const float4 gp = gp4[i];
    const int4   pd = pd4[i];
    if (pd.x) { s += __logf(ga.x) - __logf(gp.x); c += 1.f; }
    if (pd.y) { s += __logf(ga.y) - __logf(gp.y); c += 1.f; }
    if (pd.z) { s += __logf(ga.z) - __logf(gp.z); c += 1.f; }
    if (pd.w) { s += __logf(ga.w) - __logf(gp.w); c += 1.f; }
  }
#pragma unroll
  for (int m = 32; m >= 1; m >>= 1) {
    s += __shfl_xor(s, m);
    c += __shfl_xor(c, m);
  }
  if ((t & 63) == 0) { sS[t >> 6] = s; sC[t >> 6] = c; }
  __syncthreads();
  if (t == 0) {
    float S = 0.f, C = 0.f;
#pragma unroll
    for (int i = 0; i < 16; ++i) { S += sS[i]; C += sC[i]; }
    out[0] = S / fmaxf(C, 1.0f);
  }
}

extern "C" void kernel_launch(void* const* d_in, const int* in_sizes, int n_in,
                              void* d_out, int out_size, void* d_ws, size_t ws_size,
                              hipStream_t stream) {
  const float* logits = (const float*)d_in[0];
  const float* labels = (const float*)d_in[1];
  const int*   pad    = (const int*)d_in[2];
  const int*   ad     = (const int*)d_in[3];

  char* ws = (char*)d_ws;
  __bf16* qb   = (__bf16*)(ws);                 // 4 MiB
  __bf16* kb   = (__bf16*)(ws + 4194304);       // 4 MiB
  float*  cb   = (float*)(ws + 8388608);        // 32 KiB
  float*  gAll = (float*)(ws + 8421376);        // 32 KiB
  float*  gPos = (float*)(ws + 8454144);        // 32 KiB
  float*  out  = (float*)d_out;

  prep_kernel<<<4096, 256, 0, stream>>>(logits, labels, pad, qb, kb, cb, gAll, gPos);
  gemm_lse_kernel<<<dim3(64, 64), 256, 0, stream>>>(qb, kb, cb, ad, gAll, gPos);
  reduce_kernel<<<1, 1024, 0, stream>>>(gAll, gPos, pad, out);
}

// Round 6
// 127.171 us; speedup vs baseline: 1.1423x; 1.1423x over previous
//
#include <hip/hip_runtime.h>
#include <hip/hip_bf16.h>
#include <math.h>

typedef __bf16 bf16x8 __attribute__((ext_vector_type(8)));
typedef __bf16 bf16x4 __attribute__((ext_vector_type(4)));
typedef float  f32x4  __attribute__((ext_vector_type(4)));

constexpr int Nn = 8192;   // B*S
constexpr int Dd = 256;    // feature dim
constexpr float LOG2E     = 1.4426950408889634f;
constexpr float SIM_SCALE = 20.0f * LOG2E;   // (1/tau)*log2(e), tau=0.05
constexpr float SIM_BIAS  = -20.0f * LOG2E;  // fixed max = 1/tau (|q.k|<=1)

// ---------------------------------------------------------------------------
// Kernel 1: L2-normalize rows -> bf16; also init cbias / accumulators.
// ---------------------------------------------------------------------------
__global__ __launch_bounds__(256) void prep_kernel(const float* __restrict__ logits,
                                                   const float* __restrict__ labels,
                                                   const int* __restrict__ pad,
                                                   __bf16* __restrict__ qb,
                                                   __bf16* __restrict__ kb,
                                                   float* __restrict__ cbias,
                                                   float* __restrict__ g_all,
                                                   float* __restrict__ g_pos) {
  const int j = blockIdx.x * 256 + threadIdx.x;
  if (j < Nn) {
    cbias[j] = pad[j] ? 0.0f : -1e30f;
    g_all[j] = 0.0f;
    g_pos[j] = 0.0f;
  }

  const int gw   = (blockIdx.x * 256 + threadIdx.x) >> 6;
  const int lane = threadIdx.x & 63;
  const float* src;
  __bf16* dst;
  int row;
  if (gw < Nn) { src = logits; dst = qb; row = gw; }
  else         { src = labels; dst = kb; row = gw - Nn; }

  const float4 v = *reinterpret_cast<const float4*>(src + (size_t)row * Dd + lane * 4);
  float ss = v.x * v.x + v.y * v.y + v.z * v.z + v.w * v.w;
#pragma unroll
  for (int m = 32; m >= 1; m >>= 1) ss += __shfl_xor(ss, m);
  const float scale = 1.0f / fmaxf(sqrtf(ss), 1e-12f);

  bf16x4 o;
  o[0] = (__bf16)(v.x * scale);
  o[1] = (__bf16)(v.y * scale);
  o[2] = (__bf16)(v.z * scale);
  o[3] = (__bf16)(v.w * scale);
  *reinterpret_cast<bf16x4*>(dst + (size_t)row * Dd + lane * 4) = o;
}

// ---------------------------------------------------------------------------
// Kernel 2: fused sim = Q K^T / tau + masked exp-sum epilogue.
// Grid (64,64): one 128x128 tile per block. K-loop identical to R4 (75.3 us,
// 0 bank conflicts): BK=64, XOR-swizzled LDS (group' = c ^ (row&7)), VGPR
// staging. NEW epilogue: bare v_exp_f32 (__builtin_amdgcn_exp2f) and an
// LDS-transpose reduction (partials planes aliased over As/Bs) instead of
// 128 shfl_xor chains -- the epilogue was the VALU hog (42% VALUBusy, R5).
// ---------------------------------------------------------------------------
__global__ __launch_bounds__(256) void gemm_lse_kernel(const __bf16* __restrict__ qb,
                                                       const __bf16* __restrict__ kb,
                                                       const float* __restrict__ cbias,
                                                       const int* __restrict__ ad,
                                                       float* __restrict__ g_all,
                                                       float* __restrict__ g_pos) {
  __shared__ __bf16 smem[2 * 128 * 64];  // 32 KiB: As | Bs, reused by epilogue
  __bf16* As = smem;
  __bf16* Bs = smem + 128 * 64;
  float* redA = reinterpret_cast<float*>(smem);         // 128 x 32 partials
  float* redP = reinterpret_cast<float*>(smem) + 4096;  // 128 x 32 partials

  const int tid  = threadIdx.x;
  const int lane = tid & 63;
  const int w    = tid >> 6;
  const int wrow = (w >> 1) * 64;
  const int wcol = (w & 1) * 64;
  const int lq   = lane & 15;
  const int qd   = lane >> 4;
  const int rowBase = blockIdx.x * 128;
  const int colBase = blockIdx.y * 128;

  // staging geometry: 1024 16B-segments per matrix per K-chunk, 4/thread.
  // seg s: row = s>>3, group c = s&7; stored group = c ^ (row&7)
  const int sr0 = tid >> 3;            // rows sr0, sr0+32, sr0+64, sr0+96
  const int c0  = tid & 7;

  f32x4 c[4][4];
#pragma unroll
  for (int mt = 0; mt < 4; ++mt)
#pragma unroll
    for (int nt = 0; nt < 4; ++nt)
      c[mt][nt] = (f32x4){0.f, 0.f, 0.f, 0.f};

  for (int kk = 0; kk < 4; ++kk) {
    const int kOff = kk * 64;
    __syncthreads();  // prior MFMA phase done reading LDS
#pragma unroll
    for (int i = 0; i < 4; ++i) {
      const int sr  = sr0 + i * 32;
      const int dst = sr * 64 + (c0 ^ (sr & 7)) * 8;
      *reinterpret_cast<float4*>(&As[dst]) =
          *reinterpret_cast<const float4*>(qb + (size_t)(rowBase + sr) * Dd + kOff + c0 * 8);
      *reinterpret_cast<float4*>(&Bs[dst]) =
          *reinterpret_cast<const float4*>(kb + (size_t)(colBase + sr) * Dd + kOff + c0 * 8);
    }
    __syncthreads();

#pragma unroll
    for (int kq = 0; kq < 2; ++kq) {
      bf16x8 af[4], bfq[4];
      const int lg = kq * 4 + qd;  // logical 16B group within BK=64
#pragma unroll
      for (int mt = 0; mt < 4; ++mt) {
        const int r = wrow + mt * 16 + lq;
        af[mt] = *reinterpret_cast<const bf16x8*>(&As[r * 64 + (lg ^ (r & 7)) * 8]);
      }
#pragma unroll
      for (int nt = 0; nt < 4; ++nt) {
        const int r = wcol + nt * 16 + lq;
        bfq[nt] = *reinterpret_cast<const bf16x8*>(&Bs[r * 64 + (lg ^ (r & 7)) * 8]);
      }
#pragma unroll
      for (int mt = 0; mt < 4; ++mt)
#pragma unroll
        for (int nt = 0; nt < 4; ++nt)
          c[mt][nt] = __builtin_amdgcn_mfma_f32_16x16x32_bf16(af[mt], bfq[nt], c[mt][nt], 0, 0, 0);
    }
  }

  // ---- epilogue ----
  float colB[4];
  int colAd[4];
#pragma unroll
  for (int nt = 0; nt < 4; ++nt) {
    const int col = colBase + wcol + nt * 16 + lq;
    colB[nt]  = SIM_BIAS + cbias[col];
    colAd[nt] = ad[col];
  }

  __syncthreads();  // all waves done with As/Bs before reuse as partials

  // partial slot for this lane: 2 waves x 16 lq = 32 partials per row.
  // swizzled float4-group layout: group' = g ^ (row&7)  -> write 2-way (free),
  // read-phase b128 8-way (16 instrs, negligible)
  const int idx = (w & 1) * 16 + lq;
  const int g   = idx >> 2;
  const int gi  = idx & 3;

#pragma unroll
  for (int mt = 0; mt < 4; ++mt) {
#pragma unroll
    for (int r = 0; r < 4; ++r) {
      const int row   = wrow + mt * 16 + qd * 4 + r;
      const int rowAd = ad[rowBase + row];
      float a = 0.f, p = 0.f;
#pragma unroll
      for (int nt = 0; nt < 4; ++nt) {
        const float e = __builtin_amdgcn_exp2f(fmaf(c[mt][nt][r], SIM_SCALE, colB[nt]));
        a += e;
        p += (colAd[nt] == rowAd) ? e : 0.f;
      }
      const int off = row * 32 + ((g ^ (row & 7)) << 2) + gi;
      redA[off] = a;
      redP[off] = p;
    }
  }
  __syncthreads();

  if (tid < 128) {
    const int row = tid;
    float a = 0.f, p = 0.f;
#pragma unroll
    for (int gg = 0; gg < 8; ++gg) {
      const int off = row * 32 + ((gg ^ (row & 7)) << 2);
      const f32x4 va = *reinterpret_cast<const f32x4*>(&redA[off]);
      const f32x4 vp = *reinterpret_cast<const f32x4*>(&redP[off]);
      a += (va[0] + va[1]) + (va[2] + va[3]);
      p += (vp[0] + vp[1]) + (vp[2] + vp[3]);
    }
    atomicAdd(&g_all[rowBase + row], a);
    atomicAdd(&g_pos[rowBase + row], p);
  }
}

// ---------------------------------------------------------------------------
// Kernel 3: loss = mean over valid rows of log(g_all) - log(g_pos).
// ---------------------------------------------------------------------------
__global__ __launch_bounds__(1024) void reduce_kernel(const float* __restrict__ g_all,
                                                      const float* __restrict__ g_pos,
                                                      const int* __restrict__ pad,
                                                      float* __restrict__ out) {
  __shared__ float sS[16], sC[16];
  const int t = threadIdx.x;
  float s = 0.f, c = 0.f;
  const float4* ga4 = (const float4*)g_all;
  const float4* gp4 = (const float4*)g_pos;
  const int4*   pd4 = (const int4*)pad;
  for (int i = t; i < Nn / 4; i += 1024) {
    const float4 ga = ga4[i];
    const float4 gp = gp4[i];
    const int4   pd = pd4[i];
    if (pd.x) { s += __logf(ga.x) - __logf(gp.x); c += 1.f; }
    if (pd.y) { s += __logf(ga.y) - __logf(gp.y); c += 1.f; }
    if (pd.z) { s += __logf(ga.z) - __logf(gp.z); c += 1.f; }
    if (pd.w) { s += __logf(ga.w) - __logf(gp.w); c += 1.f; }
  }
#pragma unroll
  for (int m = 32; m >= 1; m >>= 1) {
    s += __shfl_xor(s, m);
    c += __shfl_xor(c, m);
  }
  if ((t & 63) == 0) { sS[t >> 6] = s; sC[t >> 6] = c; }
  __syncthreads();
  if (t == 0) {
    float S = 0.f, C = 0.f;
#pragma unroll
    for (int i = 0; i < 16; ++i) { S += sS[i]; C += sC[i]; }
    out[0] = S / fmaxf(C, 1.0f);
  }
}

extern "C" void kernel_launch(void* const* d_in, const int* in_sizes, int n_in,
                              void* d_out, int out_size, void* d_ws, size_t ws_size,
                              hipStream_t stream) {
  const float* logits = (const float*)d_in[0];
  const float* labels = (const float*)d_in[1];
  const int*   pad    = (const int*)d_in[2];
  const int*   ad     = (const int*)d_in[3];

  char* ws = (char*)d_ws;
  __bf16* qb   = (__bf16*)(ws);                 // 4 MiB
  __bf16* kb   = (__bf16*)(ws + 4194304);       // 4 MiB
  float*  cb   = (float*)(ws + 8388608);        // 32 KiB
  float*  gAll = (float*)(ws + 8421376);        // 32 KiB
  float*  gPos = (float*)(ws + 8454144);        // 32 KiB
  float*  out  = (float*)d_out;

  prep_kernel<<<4096, 256, 0, stream>>>(logits, labels, pad, qb, kb, cb, gAll, gPos);
  gemm_lse_kernel<<<dim3(64, 64), 256, 0, stream>>>(qb, kb, cb, ad, gAll, gPos);
  reduce_kernel<<<1, 1024, 0, stream>>>(gAll, gPos, pad, out);
}